// Round 3
// baseline (1725.351 us; speedup 1.0000x reference)
//
#include <hip/hip_runtime.h>
#include <hip/hip_cooperative_groups.h>

namespace cg = cooperative_groups;

#define GN      512
#define GNN     (GN * GN)
#define TILE    32
#define HALO    16          // halo radius = max steps per chunk
#define NTHR    1024
#define SURF    (17 * 64)   // one exchange surface: 16 slab rows + 1 zero pad row
#define NCHUNK  16

// lane i <- lane i-1 (wave_shl:1), lane 0 <- 0. Pure VALU, no LDS.
__device__ __forceinline__ float dpp_left(float x) {
    return __int_as_float(__builtin_amdgcn_update_dpp(
        0, __float_as_int(x), 0x130, 0xF, 0xF, true));
}
// lane i <- lane i+1 (wave_shr:1), lane 63 <- 0.
__device__ __forceinline__ float dpp_right(float x) {
    return __int_as_float(__builtin_amdgcn_update_dpp(
        0, __float_as_int(x), 0x138, 0xF, 0xF, true));
}

// Persistent cooperative kernel: all 16 temporal chunks in ONE dispatch.
// 256 blocks x 1024 threads = 1 block/CU, co-resident by cooperative launch.
// Chunk boundaries are grid.sync() (device-scope release-acquire) instead of
// kernel boundaries -- eliminates 15x (launch + L2 writeback/inv + cold
// prologue + expf recompute + LDS re-zero) of fixed overhead (~19 us each).
//
// Per-chunk structure identical to the verified round-2 kernel:
// wave w owns slab rows 4w..4w+3, lane l owns column l; vertical neighbors in
// registers, horizontal via DPP, slab boundaries via 2 ds_read + 2 ds_write
// per thread/step; in-loop barrier waits lgkmcnt only (global stores are only
// consumed after the next grid sync).
//
// Persistence bonus: after a 16-step chunk, cur/prv hold exact slices
// base+15 / base+14 for in-tile threads (trapezoid invariant) -- precisely
// the next chunk's inputs. Only halo threads (!inTile) reload from out.
// Out-of-domain cells are pinned to 0 by bm every step, so they never need
// re-zeroing, and DPP shift-in-zero edges never reach the exact region.
__global__ __launch_bounds__(NTHR)
void wave_all(const float* __restrict__ u0,
              const float* __restrict__ alpha,
              float* __restrict__ out)
{
    __shared__ __align__(16) float surf[4 * SURF];
    float* const topA = surf;
    float* const botA = surf + SURF;
    float* const topB = surf + 2 * SURF;
    float* const botB = surf + 3 * SURF;

    const int tid = threadIdx.x;
    const int w   = tid >> 6;        // wave id 0..15 = slab index
    const int l   = tid & 63;        // lane = region column

    const int bx  = blockIdx.x & 15;
    const int by  = blockIdx.x >> 4;
    const int gi0 = by * TILE - HALO + 4 * w;   // global row of my cell 0
    const int gj  = bx * TILE - HALO + l;       // global col

    for (int k = tid; k < 4 * SURF; k += NTHR) surf[k] = 0.0f;

    const float DX = 10.0f / 511.0f;
    const float K  = (5e-5f * 5e-5f) / (DX * DX);   // DT2/DX2

    float amp[4], cxs[4], cys[4];
#pragma unroll
    for (int g = 0; g < 4; ++g) {
        amp[g] = alpha[g];
        cxs[g] = alpha[4 + g];
        cys[g] = alpha[8 + g];
    }
    const float Y = -5.0f + (float)gj * DX;
    float dy2[4];
#pragma unroll
    for (int g = 0; g < 4; ++g) { const float dy = Y - cys[g]; dy2[g] = dy * dy; }

    float kc2[4], bm[4], cur[4], prv[4];
    const bool colin = ((unsigned)gj < GN);
    bool inb[4];
#pragma unroll
    for (int k = 0; k < 4; ++k) {
        const int gi = gi0 + k;
        const float X = -5.0f + (float)gi * DX;
        float cv = 2.0f;
#pragma unroll
        for (int g = 0; g < 4; ++g) {
            const float dx = X - cxs[g];
            cv += amp[g] * __expf(-(dx * dx + dy2[g]));
        }
        kc2[k] = K * (cv * cv);
        bm[k]  = (gi >= 1 && gi <= GN - 2 && gj >= 1 && gj <= GN - 2) ? 1.0f : 0.0f;
        inb[k] = colin && ((unsigned)gi < GN);
        const long off = (long)gi * GN + gj;
        cur[k] = inb[k] ? u0[off] : 0.0f;    // coalesced: 64 consecutive floats/row
        prv[k] = cur[k];                     // u_prev(0) == u0
    }

    const int sTop = (w << 6) + l;    // [w][l]   : my top-row slot / my up-source
    const int sBot = sTop + 64;       // [w+1][l] : my bottom-row slot / my dn-source
    const bool inTile = (w >= 4 && w < 12) && (l >= HALO) && (l < HALO + TILE);

    cg::grid_group grid = cg::this_grid();

// One time step (identical to verified round-2 STEP). New state lands in p;
// roles swap per call. nw0/nw3 first so their ds_writes drain under cells-1/2
// VALU. Barrier waits lgkmcnt only: global stores drain in background.
#define STEP(c, p, tRd, bRd, tWr, bWr)  do {                                          \
        const float up0 = bRd[sTop];                                                  \
        const float dn3 = tRd[sBot];                                                  \
        const float lr0 = dpp_left(c[0]) + dpp_right(c[0]);                           \
        const float lr3 = dpp_left(c[3]) + dpp_right(c[3]);                           \
        const float n0 = bm[0] * (2.0f*c[0] - p[0] + kc2[0]*(up0 + c[1] + lr0 - 4.0f*c[0])); \
        const float n3 = bm[3] * (2.0f*c[3] - p[3] + kc2[3]*(c[2] + dn3 + lr3 - 4.0f*c[3])); \
        tWr[sTop] = n0;                                                               \
        bWr[sBot] = n3;                                                               \
        const float lr1 = dpp_left(c[1]) + dpp_right(c[1]);                           \
        const float lr2 = dpp_left(c[2]) + dpp_right(c[2]);                           \
        const float n1 = bm[1] * (2.0f*c[1] - p[1] + kc2[1]*(c[0] + c[2] + lr1 - 4.0f*c[1])); \
        const float n2 = bm[2] * (2.0f*c[2] - p[2] + kc2[2]*(c[1] + c[3] + lr2 - 4.0f*c[2])); \
        p[0] = n0; p[1] = n1; p[2] = n2; p[3] = n3;                                   \
        if (inTile) { op[0] = n0; op[GN] = n1; op[2*GN] = n2; op[3*GN] = n3; }        \
        op += GNN;                                                                    \
        asm volatile("s_waitcnt lgkmcnt(0)" ::: "memory");                            \
        __builtin_amdgcn_s_barrier();                                                 \
    } while (0)

    int base = 0;
    for (int chunk = 0; chunk < NCHUNK; ++chunk) {
        const int nsteps = (chunk < NCHUNK - 1) ? 16 : 15;   // 15*16 + 15 = 255

        __syncthreads();                 // chunk 0: after zero-init; later: belt-and-braces
        topA[sTop] = cur[0];
        botA[sBot] = cur[3];
        __syncthreads();

        float* op = out + ((long)base * GNN + (long)gi0 * GN + gj);  // wild if !inTile; never deref'd

        int s = 0;
        for (; s + 2 <= nsteps; s += 2) {
            STEP(cur, prv, topA, botA, topB, botB);   // even step: read A, write B
            STEP(prv, cur, topB, botB, topA, botA);   // odd step:  read B, write A
        }
        if (s < nsteps) {                             // nsteps=15 tail
            STEP(cur, prv, topA, botA, topB, botB);
        }
        base += nsteps;

        if (chunk < NCHUNK - 1) {
            // Make in-tile stores (slices base-1, base-2) visible device-wide,
            // then refresh halo registers from neighbors' tiles.
            __threadfence();             // explicit agent-scope release (belt-and-braces)
            grid.sync();
            if (!inTile) {
                const float* c1 = out + (long)(base - 1) * GNN;   // new u_cur
                const float* c0 = out + (long)(base - 2) * GNN;   // new u_prev
#pragma unroll
                for (int k = 0; k < 4; ++k) {
                    if (inb[k]) {
                        const long o = (long)(gi0 + k) * GN + gj;
                        cur[k] = c1[o];
                        prv[k] = c0[o];
                    }
                }
            }
            // in-tile threads: cur/prv already hold exact slices base-1/base-2
        }
    }
#undef STEP
}

extern "C" void kernel_launch(void* const* d_in, const int* in_sizes, int n_in,
                              void* d_out, int out_size, void* d_ws, size_t ws_size,
                              hipStream_t stream)
{
    const float* u0    = (const float*)d_in[0];
    const float* alpha = (const float*)d_in[1];
    float*       out   = (float*)d_out;

    void* args[] = { (void*)&u0, (void*)&alpha, (void*)&out };
    hipLaunchCooperativeKernel((void*)wave_all, dim3(256), dim3(NTHR),
                               args, 0, stream);
}

// Round 4
// 671.002 us; speedup vs baseline: 2.5713x; 2.5713x over previous
//
#include <hip/hip_runtime.h>

#define GN      512
#define GNN     (GN * GN)
#define TILE    32
#define HALO    16          // halo radius = max steps per chunk
#define NTHR    1024
#define NBLK    256
#define SURF    (17 * 64)   // one exchange surface: 16 slab rows + 1 zero pad row
#define NCHUNK  16

// Inline grid-barrier state. Generation-based: no reset needed between
// launches/graph replays (gen increments monotonically, cnt returns to 0).
__device__ unsigned g_cnt = 0;
__device__ unsigned g_gen = 0;

// lane i <- lane i-1 (wave_shl:1), lane 0 <- 0. Pure VALU, no LDS.
__device__ __forceinline__ float dpp_left(float x) {
    return __int_as_float(__builtin_amdgcn_update_dpp(
        0, __float_as_int(x), 0x130, 0xF, 0xF, true));
}
// lane i <- lane i+1 (wave_shr:1), lane 63 <- 0.
__device__ __forceinline__ float dpp_right(float x) {
    return __int_as_float(__builtin_amdgcn_update_dpp(
        0, __float_as_int(x), 0x138, 0xF, 0xF, true));
}

// Persistent cooperative kernel, round-2 chunk structure, with a FULLY INLINE
// grid barrier. Round-3 post-mortem: cg::this_grid().sync() is an outlined
// __ockl_grid_sync CALL; the call ABI spilled all loop-carried state to
// scratch (VGPR_Count collapsed to 24, per-step cost 26x). This version has
// no calls anywhere: barrier is inline atomics + s_sleep spin by thread 0.
//
// Cross-XCD correctness at chunk boundaries: __syncthreads() drains each
// wave's stores (vmcnt(0)) into L2; thread0's __threadfence() is an
// agent-scope release (L2 writeback on multi-XCD gfx950); after the
// generation flips, __threadfence() again = acquire (invalidate), then
// __syncthreads() releases the block. Only then do halo threads reload.
__global__ __launch_bounds__(NTHR)
void wave_all(const float* __restrict__ u0,
              const float* __restrict__ alpha,
              float* __restrict__ out)
{
    __shared__ __align__(16) float surf[4 * SURF];
    float* const topA = surf;
    float* const botA = surf + SURF;
    float* const topB = surf + 2 * SURF;
    float* const botB = surf + 3 * SURF;

    const int tid = threadIdx.x;
    const int w   = tid >> 6;        // wave id 0..15 = slab index
    const int l   = tid & 63;        // lane = region column

    const int bx  = blockIdx.x & 15;
    const int by  = blockIdx.x >> 4;
    const int gi0 = by * TILE - HALO + 4 * w;   // global row of my cell 0
    const int gj  = bx * TILE - HALO + l;       // global col

    for (int k = tid; k < 4 * SURF; k += NTHR) surf[k] = 0.0f;

    const float DX = 10.0f / 511.0f;
    const float K  = (5e-5f * 5e-5f) / (DX * DX);   // DT2/DX2

    float amp[4], cxs[4], cys[4];
#pragma unroll
    for (int g = 0; g < 4; ++g) {
        amp[g] = alpha[g];
        cxs[g] = alpha[4 + g];
        cys[g] = alpha[8 + g];
    }
    const float Y = -5.0f + (float)gj * DX;
    float dy2[4];
#pragma unroll
    for (int g = 0; g < 4; ++g) { const float dy = Y - cys[g]; dy2[g] = dy * dy; }

    float kc2[4], bm[4], cur[4], prv[4];
    const bool colin = ((unsigned)gj < GN);
    bool inb[4];
#pragma unroll
    for (int k = 0; k < 4; ++k) {
        const int gi = gi0 + k;
        const float X = -5.0f + (float)gi * DX;
        float cv = 2.0f;
#pragma unroll
        for (int g = 0; g < 4; ++g) {
            const float dx = X - cxs[g];
            cv += amp[g] * __expf(-(dx * dx + dy2[g]));
        }
        kc2[k] = K * (cv * cv);
        bm[k]  = (gi >= 1 && gi <= GN - 2 && gj >= 1 && gj <= GN - 2) ? 1.0f : 0.0f;
        inb[k] = colin && ((unsigned)gi < GN);
        const long off = (long)gi * GN + gj;
        cur[k] = inb[k] ? u0[off] : 0.0f;    // coalesced: 64 consecutive floats/row
        prv[k] = cur[k];                     // u_prev(0) == u0
    }

    const int sTop = (w << 6) + l;    // [w][l]   : my top-row slot / my up-source
    const int sBot = sTop + 64;       // [w+1][l] : my bottom-row slot / my dn-source
    const bool inTile = (w >= 4 && w < 12) && (l >= HALO) && (l < HALO + TILE);

// One time step (identical to verified round-2 STEP). New state lands in p;
// roles swap per call. nw0/nw3 first so their ds_writes drain under cells-1/2
// VALU. Barrier waits lgkmcnt only: global stores drain in background.
#define STEP(c, p, tRd, bRd, tWr, bWr)  do {                                          \
        const float up0 = bRd[sTop];                                                  \
        const float dn3 = tRd[sBot];                                                  \
        const float lr0 = dpp_left(c[0]) + dpp_right(c[0]);                           \
        const float lr3 = dpp_left(c[3]) + dpp_right(c[3]);                           \
        const float n0 = bm[0] * (2.0f*c[0] - p[0] + kc2[0]*(up0 + c[1] + lr0 - 4.0f*c[0])); \
        const float n3 = bm[3] * (2.0f*c[3] - p[3] + kc2[3]*(c[2] + dn3 + lr3 - 4.0f*c[3])); \
        tWr[sTop] = n0;                                                               \
        bWr[sBot] = n3;                                                               \
        const float lr1 = dpp_left(c[1]) + dpp_right(c[1]);                           \
        const float lr2 = dpp_left(c[2]) + dpp_right(c[2]);                           \
        const float n1 = bm[1] * (2.0f*c[1] - p[1] + kc2[1]*(c[0] + c[2] + lr1 - 4.0f*c[1])); \
        const float n2 = bm[2] * (2.0f*c[2] - p[2] + kc2[2]*(c[1] + c[3] + lr2 - 4.0f*c[2])); \
        p[0] = n0; p[1] = n1; p[2] = n2; p[3] = n3;                                   \
        if (inTile) { op[0] = n0; op[GN] = n1; op[2*GN] = n2; op[3*GN] = n3; }        \
        op += GNN;                                                                    \
        asm volatile("s_waitcnt lgkmcnt(0)" ::: "memory");                            \
        __builtin_amdgcn_s_barrier();                                                 \
    } while (0)

    int base = 0;
    for (int chunk = 0; chunk < NCHUNK; ++chunk) {
        const int nsteps = (chunk < NCHUNK - 1) ? 16 : 15;   // 15*16 + 15 = 255

        __syncthreads();                 // chunk 0: after zero-init; later: after halo reload
        topA[sTop] = cur[0];
        botA[sBot] = cur[3];
        __syncthreads();

        float* op = out + ((long)base * GNN + (long)gi0 * GN + gj);  // wild if !inTile; never deref'd

        int s = 0;
        for (; s + 2 <= nsteps; s += 2) {
            STEP(cur, prv, topA, botA, topB, botB);   // even step: read A, write B
            STEP(prv, cur, topB, botB, topA, botA);   // odd step:  read B, write A
        }
        if (s < nsteps) {                             // nsteps=15 tail
            STEP(cur, prv, topA, botA, topB, botB);
        }
        base += nsteps;

        if (chunk < NCHUNK - 1) {
            // ---- inline grid barrier (no calls -> no spill) ----
            __syncthreads();             // drains vmcnt(0): all block stores in L2
            if (tid == 0) {
                const unsigned gen0 =
                    __hip_atomic_load(&g_gen, __ATOMIC_RELAXED, __HIP_MEMORY_SCOPE_AGENT);
                __threadfence();         // release: L2 writeback (cross-XCD visibility)
                const unsigned old =
                    __hip_atomic_fetch_add(&g_cnt, 1u, __ATOMIC_ACQ_REL, __HIP_MEMORY_SCOPE_AGENT);
                if (old == NBLK - 1) {
                    __hip_atomic_store(&g_cnt, 0u, __ATOMIC_RELAXED, __HIP_MEMORY_SCOPE_AGENT);
                    __hip_atomic_fetch_add(&g_gen, 1u, __ATOMIC_RELEASE, __HIP_MEMORY_SCOPE_AGENT);
                } else {
                    while (__hip_atomic_load(&g_gen, __ATOMIC_RELAXED,
                                             __HIP_MEMORY_SCOPE_AGENT) == gen0)
                        __builtin_amdgcn_s_sleep(2);
                }
                __threadfence();         // acquire: invalidate L1/L2 for fresh halo reads
            }
            __syncthreads();

            // Refresh halo registers from neighbors' freshly-published tiles.
            // In-tile threads: cur/prv already hold exact slices base-1/base-2.
            if (!inTile) {
                const float* c1 = out + (long)(base - 1) * GNN;   // new u_cur
                const float* c0 = out + (long)(base - 2) * GNN;   // new u_prev
#pragma unroll
                for (int k = 0; k < 4; ++k) {
                    if (inb[k]) {
                        const long o = (long)(gi0 + k) * GN + gj;
                        cur[k] = c1[o];
                        prv[k] = c0[o];
                    }
                }
            }
        }
    }
#undef STEP
}

extern "C" void kernel_launch(void* const* d_in, const int* in_sizes, int n_in,
                              void* d_out, int out_size, void* d_ws, size_t ws_size,
                              hipStream_t stream)
{
    const float* u0    = (const float*)d_in[0];
    const float* alpha = (const float*)d_in[1];
    float*       out   = (float*)d_out;

    void* args[] = { (void*)&u0, (void*)&alpha, (void*)&out };
    // Cooperative launch retained ONLY for the co-residency guarantee
    // (256 blocks / 256 CUs); sync is the inline barrier above.
    hipLaunchCooperativeKernel((void*)wave_all, dim3(NBLK), dim3(NTHR),
                               args, 0, stream);
}